// Round 6
// baseline (374.192 us; speedup 1.0000x reference)
//
#include <hip/hip_runtime.h>

#define IN_C 512
#define OUT_C 512
#define BATCH 16
#define NPX 4096   // 64*64

using bf16x8 = __attribute__((ext_vector_type(8))) __bf16;
using f32x4  = __attribute__((ext_vector_type(4))) float;

static constexpr float kConvScale = 0.014731391274719739f; // 1/sqrt(512*9)
static constexpr float kModScale  = 0.04419417382415922f;  // 1/sqrt(512)
static constexpr float kEps       = 1e-8f;

#define WT_TILE_BYTES (9 * 64 * 64)    // 36864 B per (ics, ot64) weight tile

// ---------- 1) s[b][ic] = style[b,:] . mod_weight[ic,:] * MOD_SCALE + mod_bias[ic]
__global__ void style_k(const float* __restrict__ style, const float* __restrict__ mw,
                        const float* __restrict__ mb, float* __restrict__ s) {
  __shared__ float st[IN_C];
  const int b = blockIdx.x, t = threadIdx.x;   // 512 threads
  st[t] = style[b * IN_C + t];
  __syncthreads();
  const float4* row = (const float4*)(mw + (size_t)t * IN_C);
  float acc = 0.f;
  #pragma unroll 4
  for (int i = 0; i < IN_C / 4; i++) {
    float4 v = row[i];
    float4 u = *(const float4*)(st + i * 4);
    acc += v.x * u.x + v.y * u.y + v.z * u.z + v.w * u.w;
  }
  s[b * IN_C + t] = acc * kModScale + mb[t];
}

// ---------- 2) wsq[oc][ic] = sum_tap w^2 ; wsw = bf16 weights, 64-oc-tile-major +
// XOR-swizzled. Tile (ics, ot64): logical byte B = (tap*64 + oc&63)*64 + icl*2,
// stored at B ^ (((B>>7)&7)<<4)  [(B>>7)&7 == ((oc&63)>>1)&7 since tap*32 % 8 == 0].
__global__ void wprep_k(const float* __restrict__ w, float* __restrict__ wsq,
                        char* __restrict__ wsw) {
  const int idx = blockIdx.x * 256 + threadIdx.x;  // 262144 total
  const int ic = idx & (IN_C - 1), oc = idx >> 9;
  const int ot = oc >> 6, ocl = oc & 63, ics = ic >> 5, icl = ic & 31;
  char* tile = wsw + (size_t)(ics * 8 + ot) * WT_TILE_BYTES;
  const float* p = w + (size_t)(oc * IN_C + ic) * 9;
  float q = 0.f;
  #pragma unroll
  for (int t = 0; t < 9; t++) {
    float v = p[t];
    q += v * v;
    int B = ((t * 64 + ocl) << 6) + icl * 2;
    int Bsw = B ^ (((B >> 7) & 7) << 4);
    *(__bf16*)(tile + Bsw) = (__bf16)v;
  }
  wsq[oc * IN_C + ic] = q;
}

// ---------- 3) dscale[b][oc] = CONV_SCALE * rsqrt(CONV_SCALE^2 * sum_ic s^2*wsq + eps)
__global__ void demod_k(const float* __restrict__ s, const float* __restrict__ wsq,
                        float* __restrict__ dsc) {
  __shared__ float s2[IN_C];
  const int b = blockIdx.x, t = threadIdx.x;   // 512 threads
  float sv = s[b * IN_C + t];
  s2[t] = sv * sv;
  __syncthreads();
  const float4* row = (const float4*)(wsq + (size_t)t * IN_C);
  float acc = 0.f;
  #pragma unroll 4
  for (int i = 0; i < IN_C / 4; i++) {
    float4 v = row[i];
    float4 u = *(const float4*)(s2 + i * 4);
    acc += v.x * u.x + v.y * u.y + v.z * u.z + v.w * u.w;
  }
  dsc[b * OUT_C + t] = kConvScale * rsqrtf(kConvScale * kConvScale * acc + kEps);
}

// ---------- 4) xmod[b][p][ic] = bf16(x[b][ic][p] * s[b][ic])   (NCHW -> NHWC transpose)
__global__ void modx_k(const float* __restrict__ x, const float* __restrict__ s,
                       __bf16* __restrict__ xm) {
  __shared__ __bf16 tile[64][73];
  const int t = threadIdx.x;                   // 256 threads
  const int bid = blockIdx.x;                  // 16 * 8 * 64
  const int ict = bid & 7, pt = (bid >> 3) & 63, b = bid >> 9;
  const int ic0 = ict * 64, p0 = pt * 64;
  #pragma unroll
  for (int it = 0; it < 16; it++) {
    int idx = it * 256 + t;
    int pl = idx & 63, icl = idx >> 6;
    int ic = ic0 + icl;
    float v = x[((size_t)b * IN_C + ic) * NPX + p0 + pl] * s[b * IN_C + ic];
    tile[icl][pl] = (__bf16)v;
  }
  __syncthreads();
  #pragma unroll
  for (int it = 0; it < 2; it++) {
    int idx = it * 256 + t;
    int icb = idx & 7, pl = idx >> 3;
    alignas(16) __bf16 tmp[8];
    #pragma unroll
    for (int j = 0; j < 8; j++) tmp[j] = tile[icb * 8 + j][pl];
    *(uint4*)(xm + ((size_t)b * NPX + p0 + pl) * IN_C + ic0 + icb * 8) = *(const uint4*)tmp;
  }
}

// ---------- 5) conv: NEW this round — full LDS double-buffer, ONE barrier/step
// (T3 minimum 2-phase). Block = 256 thr (4 waves), tile 64 oc x 512 px; per-wave
// shape (64oc x 128px, acc[4][8], 9-tap SGB pipeline) unchanged from R5 (245 us).
// R5's residual: per step-pair 18.4K cyc vs walls MFMA 11.2K / LDS ~12.5K — the
// ~6K gap is the vmcnt(0)-before-barrier drain of 77.8 KB glds issued with ZERO
// lookahead. Fix: dbuf x (2x42240) + dbuf w (2x36864) = 158208 B (1 block/CU);
// loop = { issue glds(s+1) -> alt buffers; compute 9 taps from cur; sync }.
// The barrier's vmcnt(0) now lands ~7K cyc after glds issue (~1.6K needed) ->
// drain ~0, and one barrier/step instead of two. 1 wave/SIMD is sufficient:
// MFMA wall 5.6K/step (single wave sustains pipe; acc reuse distance = 32 MFMAs),
// LDS wall ~6.8K/step shared-port. launch_bounds(256,1) -> 512-reg budget, no
// spill cliff (killed rounds 1/2/4). Plain __syncthreads only.

#define XROW 4224              // 66 slots * 64 B (32 ic * 2 B), no pad
#define XBUF (10 * XROW)       // 42240 B per x buffer

#define SGB __builtin_amdgcn_sched_group_barrier
// per tap: 12 DS_READ + 32 MFMA -> interleave {3 DS, 8 MFMA} x4 (R0 pattern)
#define SGB_MIX() { SGB(0x100, 3, 0); SGB(0x8, 8, 0); SGB(0x100, 3, 0); SGB(0x8, 8, 0); \
                    SGB(0x100, 3, 0); SGB(0x8, 8, 0); SGB(0x100, 3, 0); SGB(0x8, 8, 0); }
#define SGB_MFMA() { SGB(0x8, 8, 0); SGB(0x8, 8, 0); SGB(0x8, 8, 0); SGB(0x8, 8, 0); }

__global__ __launch_bounds__(256, 1)
void conv_k(const __bf16* __restrict__ xm, const char* __restrict__ wsw,
            const float* __restrict__ dsc, float* __restrict__ out) {
  __shared__ __align__(16) char xsb[2 * XBUF];           // 84480 B, dbuf input
  __shared__ __align__(16) char wsb[2 * WT_TILE_BYTES];  // 73728 B, dbuf weights
  // total 158208 B -> 1 block/CU, 4 waves

  const int tid = threadIdx.x;
  const int lane = tid & 63;
  const int wn = tid >> 6;                 // 4 waves = 4 px-quarters (128 px each)
  const int l15 = lane & 15, kb8 = lane >> 4;
  const int bid = blockIdx.x;
  const int pt = bid & 7, ot = (bid >> 3) & 7, b = bid >> 6;
  const int h0 = pt * 8, oc0 = ot * 64;

  // zero halo columns (slots 0 and 65), all 10 rows, BOTH x buffers
  if (tid < 160) {
    int bb = tid / 80, rr = (tid % 80) >> 3, side = (tid >> 2) & 1, ch = tid & 3;
    uint4 z = {0, 0, 0, 0};
    *(uint4*)(xsb + bb * XBUF + rr * XROW + side * 65 * 64 + ch * 16) = z;
  }
  // zero halo rows for edge blocks, BOTH buffers (rows skipped by XGLDS stay zero)
  if (h0 == 0) {
    uint4 z = {0, 0, 0, 0};
    for (int i = tid; i < 2 * 264; i += 256)
      *((uint4*)(xsb + (i >= 264 ? XBUF : 0)) + (i % 264)) = z;
  }
  if (h0 == 56) {
    uint4 z = {0, 0, 0, 0};
    for (int i = tid; i < 2 * 264; i += 256)
      *((uint4*)(xsb + (i >= 264 ? XBUF : 0) + 9 * XROW) + (i % 264)) = z;
  }

  // ---- input staging: one glds per row into buffer BASE; dest linear in tid;
  // source NHWC per-lane. h-guard is wave-uniform (r compile-time, h0 block-uniform).
  #define XGLDS(ICS, XB)                                                      \
    {                                                                         \
      _Pragma("unroll")                                                       \
      for (int r = 0; r < 10; r++) {                                          \
        int h = h0 + r - 1;                                                   \
        if ((unsigned)h < 64u)                                                \
          __builtin_amdgcn_global_load_lds(                                   \
              (const __attribute__((address_space(1))) void*)(xm +            \
                  ((size_t)(b * 4096 + h * 64 + (tid >> 2))) * 512 +          \
                  (ICS) * 32 + (tid & 3) * 8),                                \
              (__attribute__((address_space(3))) void*)((XB) +                \
                  r * XROW + 64 + tid * 16),                                  \
              16, 0, 0);                                                      \
      }                                                                       \
    }
  // ---- weight staging: 9 glds/thread (one tap each: 256 thr * 16 B = 4096 B/tap)
  #define WGLDS(ICS, WB)                                                      \
    {                                                                         \
      const char* wt = wsw + (size_t)((ICS) * 8 + ot) * WT_TILE_BYTES;        \
      _Pragma("unroll")                                                       \
      for (int g = 0; g < 9; g++) {                                           \
        int off = (g * 256 + tid) * 16;                                       \
        __builtin_amdgcn_global_load_lds(                                     \
            (const __attribute__((address_space(1))) void*)(wt + off),        \
            (__attribute__((address_space(3))) void*)((WB) + off), 16, 0, 0); \
      }                                                                       \
    }

  f32x4 acc[4][8];
  #pragma unroll
  for (int i = 0; i < 4; i++)
    #pragma unroll
    for (int j = 0; j < 8; j++) acc[i][j] = f32x4{0.f, 0.f, 0.f, 0.f};

  // swizzled weight read address: oc_local = fm*16 + l15 (fm adds fm*1024 B);
  // swizzle mask depends only on (l15>>1)&7
  const int swz = ((l15 >> 1) & 7) << 4;
  const int wrd_base = ((l15 << 6) + kb8 * 16) ^ swz;

  // tap-level fragment pipeline (R0 structure), reading from current buffers
  bf16x8 afA[4], bfA[8], afB[4], bfB[8];
  #define LOADT(T, AF, BF)                                                    \
    {                                                                         \
      _Pragma("unroll")                                                       \
      for (int fm = 0; fm < 4; fm++)                                          \
        AF[fm] = *(const bf16x8*)(wcur + ((T) * 4096 + fm * 1024 + wrd_base));\
      _Pragma("unroll")                                                       \
      for (int fn = 0; fn < 8; fn++) {                                        \
        int px = wn * 128 + fn * 16 + l15;                                    \
        BF[fn] = *(const bf16x8*)(xcur + ((px >> 6) + ((T) / 3)) * XROW +     \
                                  ((px & 63) + ((T) % 3)) * 64 + kb8 * 16);   \
      }                                                                       \
    }
  #define MFMAT(AF, BF)                                                       \
    {                                                                         \
      _Pragma("unroll")                                                       \
      for (int fm = 0; fm < 4; fm++)                                          \
        _Pragma("unroll")                                                     \
        for (int fn = 0; fn < 8; fn++)                                        \
          acc[fm][fn] = __builtin_amdgcn_mfma_f32_16x16x32_bf16(              \
              AF[fm], BF[fn], acc[fm][fn], 0, 0, 0);                          \
    }

  // prologue: stage step 0 into buffer 0; single drain
  XGLDS(0, xsb)
  WGLDS(0, wsb)
  __syncthreads();

  for (int s = 0; s < 16; s++) {
    const char* xcur = xsb + (s & 1) * XBUF;
    const char* wcur = wsb + (s & 1) * WT_TILE_BYTES;
    char* xnxt = xsb + ((s + 1) & 1) * XBUF;
    char* wnxt = wsb + ((s + 1) & 1) * WT_TILE_BYTES;

    if (s < 15) {                          // issue next-step stage FIRST (max lookahead)
      XGLDS(s + 1, xnxt)
      WGLDS(s + 1, wnxt)
    }

    LOADT(0, afA, bfA)
    LOADT(1, afB, bfB)
    MFMAT(afA, bfA)  SGB_MIX()             // t0 (overlaps t1 loads issued above)
    LOADT(2, afA, bfA)
    MFMAT(afB, bfB)  SGB_MIX()             // t1 || load t2
    LOADT(3, afB, bfB)
    MFMAT(afA, bfA)  SGB_MIX()             // t2 || load t3
    LOADT(4, afA, bfA)
    MFMAT(afB, bfB)  SGB_MIX()             // t3 || load t4
    LOADT(5, afB, bfB)
    MFMAT(afA, bfA)  SGB_MIX()             // t4 || load t5
    LOADT(6, afA, bfA)
    MFMAT(afB, bfB)  SGB_MIX()             // t5 || load t6
    LOADT(7, afB, bfB)
    MFMAT(afA, bfA)  SGB_MIX()             // t6 || load t7
    LOADT(8, afA, bfA)
    MFMAT(afB, bfB)  SGB_MIX()             // t7 || load t8
    MFMAT(afA, bfA)  SGB_MFMA()            // t8

    __syncthreads();                       // drains glds(s+1) (issued ~7K cyc ago)
                                           // + this step's LDS reads consumed
  }

  // epilogue: D row = oc_local (= fm*16 + kb8*4 + j), col = px (= wn*128 + fn*16 + l15)
  #pragma unroll
  for (int fm = 0; fm < 4; fm++) {
    #pragma unroll
    for (int j = 0; j < 4; j++) {
      int oc = oc0 + fm * 16 + kb8 * 4 + j;
      float dm = dsc[b * OUT_C + oc];
      float* orow = out + ((size_t)b * OUT_C + oc) * NPX + h0 * 64;
      #pragma unroll
      for (int fn = 0; fn < 8; fn++) {
        int px = wn * 128 + fn * 16 + l15;
        orow[px] = acc[fm][fn][j] * dm;
      }
    }
  }
}

extern "C" void kernel_launch(void* const* d_in, const int* in_sizes, int n_in,
                              void* d_out, int out_size, void* d_ws, size_t ws_size,
                              hipStream_t stream) {
  const float* input  = (const float*)d_in[0];
  const float* style  = (const float*)d_in[1];
  const float* weight = (const float*)d_in[2];
  const float* mod_w  = (const float*)d_in[3];
  const float* mod_b  = (const float*)d_in[4];
  float* out = (float*)d_out;

  char* p = (char*)d_ws;
  float* s    = (float*)p;  p += (size_t)BATCH * IN_C * 4;       // 32 KB
  float* dsc  = (float*)p;  p += (size_t)BATCH * OUT_C * 4;      // 32 KB
  float* wsq  = (float*)p;  p += (size_t)OUT_C * IN_C * 4;       // 1 MB
  char*  wsw  = p;          p += (size_t)16 * 8 * WT_TILE_BYTES; // 4.5 MB
  __bf16* xm  = (__bf16*)p;                                      // 64 MB

  style_k<<<BATCH, 512, 0, stream>>>(style, mod_w, mod_b, s);
  wprep_k<<<1024, 256, 0, stream>>>(weight, wsq, wsw);
  demod_k<<<BATCH, 512, 0, stream>>>(s, wsq, dsc);
  modx_k<<<BATCH * 8 * 64, 256, 0, stream>>>(input, s, xm);
  conv_k<<<BATCH * 8 * 8, 256, 0, stream>>>(xm, wsw, dsc, out);
}

// Round 7
// 358.216 us; speedup vs baseline: 1.0446x; 1.0446x over previous
//
#include <hip/hip_runtime.h>

#define IN_C 512
#define OUT_C 512
#define BATCH 16
#define NPX 4096   // 64*64

using bf16x8 = __attribute__((ext_vector_type(8))) __bf16;
using f32x4  = __attribute__((ext_vector_type(4))) float;
using f32x16 = __attribute__((ext_vector_type(16))) float;

static constexpr float kConvScale = 0.014731391274719739f; // 1/sqrt(512*9)
static constexpr float kModScale  = 0.04419417382415922f;  // 1/sqrt(512)
static constexpr float kEps       = 1e-8f;

#define WT_TILE_BYTES (9 * 64 * 64)    // 36864 B per (ics, ot64) weight tile

// ---------- 1) s[b][ic] = style[b,:] . mod_weight[ic,:] * MOD_SCALE + mod_bias[ic]
__global__ void style_k(const float* __restrict__ style, const float* __restrict__ mw,
                        const float* __restrict__ mb, float* __restrict__ s) {
  __shared__ float st[IN_C];
  const int b = blockIdx.x, t = threadIdx.x;   // 512 threads
  st[t] = style[b * IN_C + t];
  __syncthreads();
  const float4* row = (const float4*)(mw + (size_t)t * IN_C);
  float acc = 0.f;
  #pragma unroll 4
  for (int i = 0; i < IN_C / 4; i++) {
    float4 v = row[i];
    float4 u = *(const float4*)(st + i * 4);
    acc += v.x * u.x + v.y * u.y + v.z * u.z + v.w * u.w;
  }
  s[b * IN_C + t] = acc * kModScale + mb[t];
}

// ---------- 2) wsq[oc][ic] = sum_tap w^2 ; wsw = bf16 weights, 64-oc-tile-major +
// XOR-swizzled. Tile (ics, ot64): logical byte B = (tap*64 + oc&63)*64 + icl*2,
// stored at B ^ (((B>>7)&7)<<4)  [(B>>7)&7 == ((oc&63)>>1)&7 since tap*32 % 8 == 0].
__global__ void wprep_k(const float* __restrict__ w, float* __restrict__ wsq,
                        char* __restrict__ wsw) {
  const int idx = blockIdx.x * 256 + threadIdx.x;  // 262144 total
  const int ic = idx & (IN_C - 1), oc = idx >> 9;
  const int ot = oc >> 6, ocl = oc & 63, ics = ic >> 5, icl = ic & 31;
  char* tile = wsw + (size_t)(ics * 8 + ot) * WT_TILE_BYTES;
  const float* p = w + (size_t)(oc * IN_C + ic) * 9;
  float q = 0.f;
  #pragma unroll
  for (int t = 0; t < 9; t++) {
    float v = p[t];
    q += v * v;
    int B = ((t * 64 + ocl) << 6) + icl * 2;
    int Bsw = B ^ (((B >> 7) & 7) << 4);
    *(__bf16*)(tile + Bsw) = (__bf16)v;
  }
  wsq[oc * IN_C + ic] = q;
}

// ---------- 3) dscale[b][oc] = CONV_SCALE * rsqrt(CONV_SCALE^2 * sum_ic s^2*wsq + eps)
__global__ void demod_k(const float* __restrict__ s, const float* __restrict__ wsq,
                        float* __restrict__ dsc) {
  __shared__ float s2[IN_C];
  const int b = blockIdx.x, t = threadIdx.x;   // 512 threads
  float sv = s[b * IN_C + t];
  s2[t] = sv * sv;
  __syncthreads();
  const float4* row = (const float4*)(wsq + (size_t)t * IN_C);
  float acc = 0.f;
  #pragma unroll 4
  for (int i = 0; i < IN_C / 4; i++) {
    float4 v = row[i];
    float4 u = *(const float4*)(s2 + i * 4);
    acc += v.x * u.x + v.y * u.y + v.z * u.z + v.w * u.w;
  }
  dsc[b * OUT_C + t] = kConvScale * rsqrtf(kConvScale * kConvScale * acc + kEps);
}

// ---------- 4) xmod[b][p][ic] = bf16(x[b][ic][p] * s[b][ic])   (NCHW -> NHWC transpose)
__global__ void modx_k(const float* __restrict__ x, const float* __restrict__ s,
                       __bf16* __restrict__ xm) {
  __shared__ __bf16 tile[64][73];
  const int t = threadIdx.x;                   // 256 threads
  const int bid = blockIdx.x;                  // 16 * 8 * 64
  const int ict = bid & 7, pt = (bid >> 3) & 63, b = bid >> 9;
  const int ic0 = ict * 64, p0 = pt * 64;
  #pragma unroll
  for (int it = 0; it < 16; it++) {
    int idx = it * 256 + t;
    int pl = idx & 63, icl = idx >> 6;
    int ic = ic0 + icl;
    float v = x[((size_t)b * IN_C + ic) * NPX + p0 + pl] * s[b * IN_C + ic];
    tile[icl][pl] = (__bf16)v;
  }
  __syncthreads();
  #pragma unroll
  for (int it = 0; it < 2; it++) {
    int idx = it * 256 + t;
    int icb = idx & 7, pl = idx >> 3;
    alignas(16) __bf16 tmp[8];
    #pragma unroll
    for (int j = 0; j < 8; j++) tmp[j] = tile[icb * 8 + j][pl];
    *(uint4*)(xm + ((size_t)b * NPX + p0 + pl) * IN_C + ic0 + icb * 8) = *(const uint4*)tmp;
  }
}

// ---------- 5) conv: R5 structure (2 blocks/CU x 4 waves, 64oc x 512px, 245 us)
// + ONE change: 16x16x32 MFMA -> 32x32x16 MFMA. ubench: 32x32 runs at 2495 TF
// (99.8% dense peak) vs 16x16's 2075 -> per tap 16x32.3=516 cyc vs 32x19.4=621,
// -17% on the MFMA wall (which is the serial 61% of the 18.4K step-pair:
// MfmaUtil 59% == 11.2K/18.4K). LDS bytes, fragment regs (96), acc regs (128)
// all unchanged. Wave tile stays 64oc x 128px = 2x4 tiles of 32x32, acc f32x16.
// Layout consequence: 32-px B fragments need a per-slot chunk XOR (f=(slot>>1)&3)
// to stay bank-uniform; applied via pre-swizzled glds SOURCE (LDS dest linear,
// m173 pattern) + same XOR on read. A-side reuses wprep's existing swizzle
// ((ocl>>1)&7 is oct-invariant). kc-outer MFMA order -> same-acc dep distance 8.

#define XROW 4224              // 66 slots * 64 B (32 ic * 2 B), no pad
#define SGB __builtin_amdgcn_sched_group_barrier
// per tap: 12 DS_READ + 16 MFMA -> interleave {3 DS, 4 MFMA} x4
#define SGB_MIX() { SGB(0x100, 3, 0); SGB(0x8, 4, 0); SGB(0x100, 3, 0); SGB(0x8, 4, 0); \
                    SGB(0x100, 3, 0); SGB(0x8, 4, 0); SGB(0x100, 3, 0); SGB(0x8, 4, 0); }
#define SGB_MFMA() { SGB(0x8, 4, 0); SGB(0x8, 4, 0); SGB(0x8, 4, 0); SGB(0x8, 4, 0); }

__global__ __launch_bounds__(256, 2)
void conv_k(const __bf16* __restrict__ xm, const char* __restrict__ wsw,
            const float* __restrict__ dsc, float* __restrict__ out) {
  __shared__ __align__(16) char xsb[10 * XROW];      // 42240 B input tile
  __shared__ __align__(16) char wsb[WT_TILE_BYTES];  // 36864 B weight tile
  // total 79104 B -> 2 blocks/CU (8 waves/CU, 2/SIMD)

  const int tid = threadIdx.x;
  const int lane = tid & 63;
  const int wn = tid >> 6;                 // 4 waves = 4 px-quarters (128 px each)
  const int l31 = lane & 31, hi = lane >> 5;
  const int bid = blockIdx.x;
  const int pt = bid & 7, ot = (bid >> 3) & 7, b = bid >> 6;
  const int h0 = pt * 8, oc0 = ot * 64;

  // zero halo columns (slots 0 and 65), all 10 rows (all 4 chunks -> layout-proof)
  if (tid < 80) {
    int r = tid >> 3, side = (tid >> 2) & 1, ch = tid & 3;
    uint4 z = {0, 0, 0, 0};
    *(uint4*)(xsb + r * XROW + side * 65 * 64 + ch * 16) = z;
  }
  // zero halo rows for edge blocks (rows skipped by XGLDS stay zero all steps)
  if (h0 == 0) {
    uint4 z = {0, 0, 0, 0};
    for (int i = tid; i < 264; i += 256) ((uint4*)xsb)[i] = z;
  }
  if (h0 == 56) {
    uint4 z = {0, 0, 0, 0};
    for (int i = tid; i < 264; i += 256) ((uint4*)(xsb + 9 * XROW))[i] = z;
  }

  // ---- input staging: dest linear in tid; SOURCE chunk pre-permuted so LDS
  // holds chunk c at stored position c ^ f(slot), f = (slot>>1)&3 (slot = pix+1).
  const int chv = ((tid & 3) ^ ((((tid >> 2) + 1) >> 1) & 3)) * 8;  // src elem off
  #define XGLDS(ICS)                                                          \
    {                                                                         \
      _Pragma("unroll")                                                       \
      for (int r = 0; r < 10; r++) {                                          \
        int h = h0 + r - 1;                                                   \
        if ((unsigned)h < 64u)                                                \
          __builtin_amdgcn_global_load_lds(                                   \
              (const __attribute__((address_space(1))) void*)(xm +            \
                  ((size_t)(b * 4096 + h * 64 + (tid >> 2))) * 512 +          \
                  (ICS) * 32 + chv),                                          \
              (__attribute__((address_space(3))) void*)(xsb +                 \
                  r * XROW + 64 + tid * 16),                                  \
              16, 0, 0);                                                      \
      }                                                                       \
    }
  // ---- weight staging: 9 glds/thread (one tap each), linear, src pre-swizzled
  #define WGLDS(ICS)                                                          \
    {                                                                         \
      const char* wt = wsw + (size_t)((ICS) * 8 + ot) * WT_TILE_BYTES;        \
      _Pragma("unroll")                                                       \
      for (int g = 0; g < 9; g++) {                                           \
        int off = (g * 256 + tid) * 16;                                       \
        __builtin_amdgcn_global_load_lds(                                     \
            (const __attribute__((address_space(1))) void*)(wt + off),        \
            (__attribute__((address_space(3))) void*)(wsb + off), 16, 0, 0);  \
      }                                                                       \
    }

  f32x16 acc[2][4];
  #pragma unroll
  for (int o = 0; o < 2; o++)
    #pragma unroll
    for (int p = 0; p < 4; p++)
      #pragma unroll
      for (int i = 0; i < 16; i++) acc[o][p][i] = 0.f;

  // A read base: row = oct*32 + l31, chunk = kc*2 + hi; stored = logical ^ swzA
  // (swzA = ((l31>>1)&7)<<4, oct/tap-invariant). kc toggles via XOR bit5.
  const int swzA = ((l31 >> 1) & 7) << 4;
  const int wrdA = ((l31 << 6) + (hi << 4)) ^ swzA;

  // B read bases per (pxt, dx): slot = (pxt&1)*32 + l31 + dx, f = (slot>>1)&3;
  // byte = rowbase + slot*64 + ((hi^ (f&1))<<4) + ((f>>1)<<5); kc via XOR bit5.
  int xb[12];
  #pragma unroll
  for (int p = 0; p < 4; p++)
    #pragma unroll
    for (int d = 0; d < 3; d++) {
      int slot = (p & 1) * 32 + l31 + d;
      int f = (slot >> 1) & 3;
      xb[p * 3 + d] = (wn * 2 + (p >> 1)) * XROW + slot * 64 +
                      ((hi ^ (f & 1)) << 4) + ((f >> 1) << 5);
    }

  // tap-level fragment pipeline: AF[oct*2+kc] (4), BF[pxt*2+kc] (8)
  bf16x8 afA[4], bfA[8], afB[4], bfB[8];
  #define LOADT(T, AF, BF)                                                    \
    {                                                                         \
      _Pragma("unroll")                                                       \
      for (int oct = 0; oct < 2; oct++)                                       \
        _Pragma("unroll")                                                     \
        for (int kc = 0; kc < 2; kc++)                                        \
          AF[oct * 2 + kc] = *(const bf16x8*)(wsb + (T) * 4096 +              \
              oct * 2048 + (wrdA ^ (kc << 5)));                               \
      _Pragma("unroll")                                                       \
      for (int pxt = 0; pxt < 4; pxt++)                                       \
        _Pragma("unroll")                                                     \
        for (int kc = 0; kc < 2; kc++)                                        \
          BF[pxt * 2 + kc] = *(const bf16x8*)(xsb + ((T) / 3) * XROW +        \
              (xb[pxt * 3 + (T) % 3] ^ (kc << 5)));                           \
    }
  // kc OUTER: 8 independent MFMAs between same-acc dependents
  #define MFMAT(AF, BF)                                                       \
    {                                                                         \
      _Pragma("unroll")                                                       \
      for (int kc = 0; kc < 2; kc++)                                          \
        _Pragma("unroll")                                                     \
        for (int oct = 0; oct < 2; oct++)                                     \
          _Pragma("unroll")                                                   \
          for (int pxt = 0; pxt < 4; pxt++)                                   \
            acc[oct][pxt] = __builtin_amdgcn_mfma_f32_32x32x16_bf16(          \
                AF[oct * 2 + kc], BF[pxt * 2 + kc], acc[oct][pxt], 0, 0, 0);  \
    }

  for (int s = 0; s < 16; s++) {
    __syncthreads();                       // (a) prev step's LDS reads consumed
    XGLDS(s)
    WGLDS(s)
    __syncthreads();                       // (b) drains glds -> x+w resident
    // (co-resident second block covers this block's stage/drain window)

    LOADT(0, afA, bfA)
    LOADT(1, afB, bfB)
    MFMAT(afA, bfA)  SGB_MIX()             // t0 (overlaps t1 loads issued above)
    LOADT(2, afA, bfA)
    MFMAT(afB, bfB)  SGB_MIX()             // t1 || load t2
    LOADT(3, afB, bfB)
    MFMAT(afA, bfA)  SGB_MIX()             // t2 || load t3
    LOADT(4, afA, bfA)
    MFMAT(afB, bfB)  SGB_MIX()             // t3 || load t4
    LOADT(5, afB, bfB)
    MFMAT(afA, bfA)  SGB_MIX()             // t4 || load t5
    LOADT(6, afA, bfA)
    MFMAT(afB, bfB)  SGB_MIX()             // t5 || load t6
    LOADT(7, afB, bfB)
    MFMAT(afA, bfA)  SGB_MIX()             // t6 || load t7
    LOADT(8, afA, bfA)
    MFMAT(afB, bfB)  SGB_MIX()             // t7 || load t8
    MFMAT(afA, bfA)  SGB_MFMA()            // t8
  }

  // epilogue: C/D 32x32 layout: col = lane&31 (px), row = (reg&3)+8*(reg>>2)+4*hi
  #pragma unroll
  for (int oct = 0; oct < 2; oct++) {
    #pragma unroll
    for (int reg = 0; reg < 16; reg++) {
      int oc = oc0 + oct * 32 + (reg & 3) + 8 * (reg >> 2) + hi * 4;
      float dm = dsc[b * OUT_C + oc];
      float* orow = out + ((size_t)b * OUT_C + oc) * NPX + h0 * 64;
      #pragma unroll
      for (int pxt = 0; pxt < 4; pxt++) {
        int px = wn * 128 + pxt * 32 + l31;
        orow[px] = acc[oct][pxt][reg] * dm;
      }
    }
  }
}

extern "C" void kernel_launch(void* const* d_in, const int* in_sizes, int n_in,
                              void* d_out, int out_size, void* d_ws, size_t ws_size,
                              hipStream_t stream) {
  const float* input  = (const float*)d_in[0];
  const float* style  = (const float*)d_in[1];
  const float* weight = (const float*)d_in[2];
  const float* mod_w  = (const float*)d_in[3];
  const float* mod_b  = (const float*)d_in[4];
  float* out = (float*)d_out;

  char* p = (char*)d_ws;
  float* s    = (float*)p;  p += (size_t)BATCH * IN_C * 4;       // 32 KB
  float* dsc  = (float*)p;  p += (size_t)BATCH * OUT_C * 4;      // 32 KB
  float* wsq  = (float*)p;  p += (size_t)OUT_C * IN_C * 4;       // 1 MB
  char*  wsw  = p;          p += (size_t)16 * 8 * WT_TILE_BYTES; // 4.5 MB
  __bf16* xm  = (__bf16*)p;                                      // 64 MB

  style_k<<<BATCH, 512, 0, stream>>>(style, mod_w, mod_b, s);
  wprep_k<<<1024, 256, 0, stream>>>(weight, wsq, wsw);
  demod_k<<<BATCH, 512, 0, stream>>>(s, wsq, dsc);
  modx_k<<<BATCH * 8 * 64, 256, 0, stream>>>(input, s, xm);
  conv_k<<<BATCH * 8 * 8, 256, 0, stream>>>(xm, wsw, dsc, out);
}

// Round 8
// 352.848 us; speedup vs baseline: 1.0605x; 1.0152x over previous
//
#include <hip/hip_runtime.h>

#define IN_C 512
#define OUT_C 512
#define BATCH 16
#define NPX 4096   // 64*64

using bf16x8 = __attribute__((ext_vector_type(8))) __bf16;
using f32x4  = __attribute__((ext_vector_type(4))) float;

static constexpr float kConvScale = 0.014731391274719739f; // 1/sqrt(512*9)
static constexpr float kModScale  = 0.04419417382415922f;  // 1/sqrt(512)
static constexpr float kEps       = 1e-8f;

#define WT_TILE_BYTES (9 * 64 * 64)    // 36864 B per (ics, ot64) weight tile

// ---------- 1) s[b][ic] = style[b,:] . mod_weight[ic,:] * MOD_SCALE + mod_bias[ic]
__global__ void style_k(const float* __restrict__ style, const float* __restrict__ mw,
                        const float* __restrict__ mb, float* __restrict__ s) {
  __shared__ float st[IN_C];
  const int b = blockIdx.x, t = threadIdx.x;   // 512 threads
  st[t] = style[b * IN_C + t];
  __syncthreads();
  const float4* row = (const float4*)(mw + (size_t)t * IN_C);
  float acc = 0.f;
  #pragma unroll 4
  for (int i = 0; i < IN_C / 4; i++) {
    float4 v = row[i];
    float4 u = *(const float4*)(st + i * 4);
    acc += v.x * u.x + v.y * u.y + v.z * u.z + v.w * u.w;
  }
  s[b * IN_C + t] = acc * kModScale + mb[t];
}

// ---------- 2) wsq[oc][ic] = sum_tap w^2 ; wsw = bf16 weights, 64-oc-tile-major +
// XOR-swizzled. Tile (ics, ot64): logical byte B = (tap*64 + oc&63)*64 + icl*2,
// stored at B ^ (((B>>7)&7)<<4)  [(B>>7)&7 == ((oc&63)>>1)&7 since tap*32 % 8 == 0].
__global__ void wprep_k(const float* __restrict__ w, float* __restrict__ wsq,
                        char* __restrict__ wsw) {
  const int idx = blockIdx.x * 256 + threadIdx.x;  // 262144 total
  const int ic = idx & (IN_C - 1), oc = idx >> 9;
  const int ot = oc >> 6, ocl = oc & 63, ics = ic >> 5, icl = ic & 31;
  char* tile = wsw + (size_t)(ics * 8 + ot) * WT_TILE_BYTES;
  const float* p = w + (size_t)(oc * IN_C + ic) * 9;
  float q = 0.f;
  #pragma unroll
  for (int t = 0; t < 9; t++) {
    float v = p[t];
    q += v * v;
    int B = ((t * 64 + ocl) << 6) + icl * 2;
    int Bsw = B ^ (((B >> 7) & 7) << 4);
    *(__bf16*)(tile + Bsw) = (__bf16)v;
  }
  wsq[oc * IN_C + ic] = q;
}

// ---------- 3) dscale[b][oc] = CONV_SCALE * rsqrt(CONV_SCALE^2 * sum_ic s^2*wsq + eps)
__global__ void demod_k(const float* __restrict__ s, const float* __restrict__ wsq,
                        float* __restrict__ dsc) {
  __shared__ float s2[IN_C];
  const int b = blockIdx.x, t = threadIdx.x;   // 512 threads
  float sv = s[b * IN_C + t];
  s2[t] = sv * sv;
  __syncthreads();
  const float4* row = (const float4*)(wsq + (size_t)t * IN_C);
  float acc = 0.f;
  #pragma unroll 4
  for (int i = 0; i < IN_C / 4; i++) {
    float4 v = row[i];
    float4 u = *(const float4*)(s2 + i * 4);
    acc += v.x * u.x + v.y * u.y + v.z * u.z + v.w * u.w;
  }
  dsc[b * OUT_C + t] = kConvScale * rsqrtf(kConvScale * kConvScale * acc + kEps);
}

// ---------- 4) xmod[b][p][ic] = bf16(x[b][ic][p] * s[b][ic])   (NCHW -> NHWC)
// NEW this round: float4 global loads (16 B/lane, G13) — was 16 scalar-f32 iters.
// LDS tile / transpose-store phase unchanged.
__global__ void modx_k(const float* __restrict__ x, const float* __restrict__ s,
                       __bf16* __restrict__ xm) {
  __shared__ __bf16 tile[64][73];
  const int t = threadIdx.x;                   // 256 threads
  const int bid = blockIdx.x;                  // 16 * 8 * 64
  const int ict = bid & 7, pt = (bid >> 3) & 63, b = bid >> 9;
  const int ic0 = ict * 64, p0 = pt * 64;
  #pragma unroll
  for (int it = 0; it < 4; it++) {             // 1024 float4 = 64 ic x 16 float4
    int idx = it * 256 + t;
    int pl4 = idx & 15, icl = idx >> 4;
    int ic = ic0 + icl;
    float4 v = *(const float4*)(x + ((size_t)b * IN_C + ic) * NPX + p0 + pl4 * 4);
    float sv = s[b * IN_C + ic];
    tile[icl][pl4 * 4 + 0] = (__bf16)(v.x * sv);
    tile[icl][pl4 * 4 + 1] = (__bf16)(v.y * sv);
    tile[icl][pl4 * 4 + 2] = (__bf16)(v.z * sv);
    tile[icl][pl4 * 4 + 3] = (__bf16)(v.w * sv);
  }
  __syncthreads();
  #pragma unroll
  for (int it = 0; it < 2; it++) {
    int idx = it * 256 + t;
    int icb = idx & 7, pl = idx >> 3;
    alignas(16) __bf16 tmp[8];
    #pragma unroll
    for (int j = 0; j < 8; j++) tmp[j] = tile[icb * 8 + j][pl];
    *(uint4*)(xm + ((size_t)b * NPX + p0 + pl) * IN_C + ic0 + icb * 8) = *(const uint4*)tmp;
  }
}

// ---------- 5) conv: R5 structure byte-identical (2 blocks/CU x 4 waves,
// 64oc x 512px, 16x16x32 MFMA, 245 us) + ONE change: T5 s_setprio(1/0) around
// each MFMA cluster. Mechanism: the two co-resident blocks have independent
// barriers -> waves on a SIMD are often in DIFFERENT phases (one staging/
// ds-waiting, one MFMA-ready). setprio biases issue toward the MFMA-phase wave
// (catalog m218b/m224: +21-39% with role-split; m190: null when lockstep).
// Zero register cost (SALU) -> spill-free guarantee preserved.
// (R7's 32x32 swap reverted: bank conflicts +50% ate the MFMA-wall gain.)

#define XROW 4224              // 66 slots * 64 B (32 ic * 2 B), no pad

#define SGB __builtin_amdgcn_sched_group_barrier
// per tap: 12 DS_READ + 32 MFMA -> interleave {3 DS, 8 MFMA} x4 (R0 pattern)
#define SGB_MIX() { SGB(0x100, 3, 0); SGB(0x8, 8, 0); SGB(0x100, 3, 0); SGB(0x8, 8, 0); \
                    SGB(0x100, 3, 0); SGB(0x8, 8, 0); SGB(0x100, 3, 0); SGB(0x8, 8, 0); }
#define SGB_MFMA() { SGB(0x8, 8, 0); SGB(0x8, 8, 0); SGB(0x8, 8, 0); SGB(0x8, 8, 0); }
#define PRIO1() __builtin_amdgcn_s_setprio(1)
#define PRIO0() __builtin_amdgcn_s_setprio(0)

__global__ __launch_bounds__(256, 2)
void conv_k(const __bf16* __restrict__ xm, const char* __restrict__ wsw,
            const float* __restrict__ dsc, float* __restrict__ out) {
  __shared__ __align__(16) char xsb[10 * XROW];      // 42240 B input tile
  __shared__ __align__(16) char wsb[WT_TILE_BYTES];  // 36864 B weight tile
  // total 79104 B -> 2 blocks/CU (8 waves/CU, 2/SIMD)

  const int tid = threadIdx.x;
  const int lane = tid & 63;
  const int wn = tid >> 6;                 // 4 waves = 4 px-quarters (128 px each)
  const int l15 = lane & 15, kb8 = lane >> 4;
  const int bid = blockIdx.x;
  const int pt = bid & 7, ot = (bid >> 3) & 7, b = bid >> 6;
  const int h0 = pt * 8, oc0 = ot * 64;

  // zero halo columns (slots 0 and 65), all 10 rows; never overwritten
  if (tid < 80) {
    int r = tid >> 3, side = (tid >> 2) & 1, ch = tid & 3;
    uint4 z = {0, 0, 0, 0};
    *(uint4*)(xsb + r * XROW + side * 65 * 64 + ch * 16) = z;
  }
  // zero halo rows for edge blocks (rows skipped by XGLDS stay zero all steps)
  if (h0 == 0) {
    uint4 z = {0, 0, 0, 0};
    for (int i = tid; i < 264; i += 256) ((uint4*)xsb)[i] = z;
  }
  if (h0 == 56) {
    uint4 z = {0, 0, 0, 0};
    for (int i = tid; i < 264; i += 256) ((uint4*)(xsb + 9 * XROW))[i] = z;
  }

  // ---- input staging: one glds per row; dest linear in tid (row interior = 4 KB);
  // source NHWC per-lane. h-guard is wave-uniform (r compile-time, h0 block-uniform).
  #define XGLDS(ICS)                                                          \
    {                                                                         \
      _Pragma("unroll")                                                       \
      for (int r = 0; r < 10; r++) {                                          \
        int h = h0 + r - 1;                                                   \
        if ((unsigned)h < 64u)                                                \
          __builtin_amdgcn_global_load_lds(                                   \
              (const __attribute__((address_space(1))) void*)(xm +            \
                  ((size_t)(b * 4096 + h * 64 + (tid >> 2))) * 512 +          \
                  (ICS) * 32 + (tid & 3) * 8),                                \
              (__attribute__((address_space(3))) void*)(xsb +                 \
                  r * XROW + 64 + tid * 16),                                  \
              16, 0, 0);                                                      \
      }                                                                       \
    }
  // ---- weight staging: 9 glds/thread (one tap each: 256 thr * 16 B = 4096 B/tap)
  #define WGLDS(ICS)                                                          \
    {                                                                         \
      const char* wt = wsw + (size_t)((ICS) * 8 + ot) * WT_TILE_BYTES;        \
      _Pragma("unroll")                                                       \
      for (int g = 0; g < 9; g++) {                                           \
        int off = (g * 256 + tid) * 16;                                       \
        __builtin_amdgcn_global_load_lds(                                     \
            (const __attribute__((address_space(1))) void*)(wt + off),        \
            (__attribute__((address_space(3))) void*)(wsb + off), 16, 0, 0);  \
      }                                                                       \
    }

  f32x4 acc[4][8];
  #pragma unroll
  for (int i = 0; i < 4; i++)
    #pragma unroll
    for (int j = 0; j < 8; j++) acc[i][j] = f32x4{0.f, 0.f, 0.f, 0.f};

  // swizzled weight read address: oc_local = fm*16 + l15 (fm adds fm*1024 B);
  // swizzle mask depends only on (l15>>1)&7
  const int swz = ((l15 >> 1) & 7) << 4;
  const int wrd_base = ((l15 << 6) + kb8 * 16) ^ swz;

  // tap-level fragment pipeline (R0 structure)
  bf16x8 afA[4], bfA[8], afB[4], bfB[8];
  #define LOADT(T, AF, BF)                                                    \
    {                                                                         \
      _Pragma("unroll")                                                       \
      for (int fm = 0; fm < 4; fm++)                                          \
        AF[fm] = *(const bf16x8*)(wsb + ((T) * 4096 + fm * 1024 + wrd_base)); \
      _Pragma("unroll")                                                       \
      for (int fn = 0; fn < 8; fn++) {                                        \
        int px = wn * 128 + fn * 16 + l15;                                    \
        BF[fn] = *(const bf16x8*)(xsb + ((px >> 6) + ((T) / 3)) * XROW +      \
                                  ((px & 63) + ((T) % 3)) * 64 + kb8 * 16);   \
      }                                                                       \
    }
  #define MFMAT(AF, BF)                                                       \
    {                                                                         \
      _Pragma("unroll")                                                       \
      for (int fm = 0; fm < 4; fm++)                                          \
        _Pragma("unroll")                                                     \
        for (int fn = 0; fn < 8; fn++)                                        \
          acc[fm][fn] = __builtin_amdgcn_mfma_f32_16x16x32_bf16(              \
              AF[fm], BF[fn], acc[fm][fn], 0, 0, 0);                          \
    }

  for (int s = 0; s < 16; s++) {
    __syncthreads();                       // (a) prev step's LDS reads consumed
    XGLDS(s)
    WGLDS(s)
    __syncthreads();                       // (b) drains glds -> x+w resident
    // (co-resident second block covers this block's stage/drain window)

    LOADT(0, afA, bfA)
    LOADT(1, afB, bfB)
    PRIO1(); MFMAT(afA, bfA); PRIO0();  SGB_MIX()   // t0
    LOADT(2, afA, bfA)
    PRIO1(); MFMAT(afB, bfB); PRIO0();  SGB_MIX()   // t1 || load t2
    LOADT(3, afB, bfB)
    PRIO1(); MFMAT(afA, bfA); PRIO0();  SGB_MIX()   // t2 || load t3
    LOADT(4, afA, bfA)
    PRIO1(); MFMAT(afB, bfB); PRIO0();  SGB_MIX()   // t3 || load t4
    LOADT(5, afB, bfB)
    PRIO1(); MFMAT(afA, bfA); PRIO0();  SGB_MIX()   // t4 || load t5
    LOADT(6, afA, bfA)
    PRIO1(); MFMAT(afB, bfB); PRIO0();  SGB_MIX()   // t5 || load t6
    LOADT(7, afB, bfB)
    PRIO1(); MFMAT(afA, bfA); PRIO0();  SGB_MIX()   // t6 || load t7
    LOADT(8, afA, bfA)
    PRIO1(); MFMAT(afB, bfB); PRIO0();  SGB_MIX()   // t7 || load t8
    PRIO1(); MFMAT(afA, bfA); PRIO0();  SGB_MFMA()  // t8
  }

  // epilogue: D row = oc_local (= fm*16 + kb8*4 + j), col = px (= wn*128 + fn*16 + l15)
  #pragma unroll
  for (int fm = 0; fm < 4; fm++) {
    #pragma unroll
    for (int j = 0; j < 4; j++) {
      int oc = oc0 + fm * 16 + kb8 * 4 + j;
      float dm = dsc[b * OUT_C + oc];
      float* orow = out + ((size_t)b * OUT_C + oc) * NPX + h0 * 64;
      #pragma unroll
      for (int fn = 0; fn < 8; fn++) {
        int px = wn * 128 + fn * 16 + l15;
        orow[px] = acc[fm][fn][j] * dm;
      }
    }
  }
}

extern "C" void kernel_launch(void* const* d_in, const int* in_sizes, int n_in,
                              void* d_out, int out_size, void* d_ws, size_t ws_size,
                              hipStream_t stream) {
  const float* input  = (const float*)d_in[0];
  const float* style  = (const float*)d_in[1];
  const float* weight = (const float*)d_in[2];
  const float* mod_w  = (const float*)d_in[3];
  const float* mod_b  = (const float*)d_in[4];
  float* out = (float*)d_out;

  char* p = (char*)d_ws;
  float* s    = (float*)p;  p += (size_t)BATCH * IN_C * 4;       // 32 KB
  float* dsc  = (float*)p;  p += (size_t)BATCH * OUT_C * 4;      // 32 KB
  float* wsq  = (float*)p;  p += (size_t)OUT_C * IN_C * 4;       // 1 MB
  char*  wsw  = p;          p += (size_t)16 * 8 * WT_TILE_BYTES; // 4.5 MB
  __bf16* xm  = (__bf16*)p;                                      // 64 MB

  style_k<<<BATCH, 512, 0, stream>>>(style, mod_w, mod_b, s);
  wprep_k<<<1024, 256, 0, stream>>>(weight, wsq, wsw);
  demod_k<<<BATCH, 512, 0, stream>>>(s, wsq, dsc);
  modx_k<<<BATCH * 8 * 64, 256, 0, stream>>>(input, s, xm);
  conv_k<<<BATCH * 8 * 8, 256, 0, stream>>>(xm, wsw, dsc, out);
}